// Round 1
// 476.596 us; speedup vs baseline: 1.0836x; 1.0836x over previous
//
#include <hip/hip_runtime.h>
#include <stdint.h>

typedef unsigned short u16;
typedef unsigned int   u32;

#define T_LEN 4000
#define NEG_INF (-3.4028234663852886e38f)

typedef __bf16 bf16x8 __attribute__((ext_vector_type(8)));
typedef float  f32x4  __attribute__((ext_vector_type(4)));

__device__ __forceinline__ u16 f2bf(float f){
    union { float f; u32 i; } v; v.f = f;
    u32 u = v.i;
    u32 r = (u + 0x7FFFu + ((u >> 16) & 1u)) >> 16;
    return (u16)r;
}
__device__ __forceinline__ float tanh_fast(float x){
    float ax = fabsf(x);
    float a = __expf(-2.0f * ax);
    float t = (1.0f - a) / (1.0f + a);
    return copysignf(t, x);
}
__device__ __forceinline__ u32 rotl32(u32 x, int n){ return (x << n) | (x >> (32 - n)); }

// async global->LDS, 16B per lane (global_load_lds_dwordx4).
// LDS dest must be linear in lane order: base + lane*16.
__device__ __forceinline__ void gll16(const void* g, void* l){
    __builtin_amdgcn_global_load_lds(
        (__attribute__((address_space(1))) void*)g,
        (__attribute__((address_space(3))) void*)l, 16, 0, 0);
}

// jax.random.normal(jax.random.key(123), (16,4000), f32) — threefry2x32. [verified]
__device__ float jax_noise(u32 idx){
    const u32 k0 = 0u, k1 = 123u;
    const u32 k2 = k0 ^ k1 ^ 0x1BD11BDAu;
    u32 x0 = k0;
    u32 x1 = idx + k1;
#define RND(r) { x0 += x1; x1 = rotl32(x1, r); x1 ^= x0; }
    RND(13) RND(15) RND(26) RND(6)   x0 += k1; x1 += k2 + 1u;
    RND(17) RND(29) RND(16) RND(24)  x0 += k2; x1 += k0 + 2u;
    RND(13) RND(15) RND(26) RND(6)   x0 += k0; x1 += k1 + 3u;
    RND(17) RND(29) RND(16) RND(24)  x0 += k1; x1 += k2 + 4u;
    RND(13) RND(15) RND(26) RND(6)   x0 += k2; x1 += k0 + 5u;
#undef RND
    u32 bits = x0 ^ x1;
    union { u32 i; float f; } u;
    u.i = (bits >> 9) | 0x3F800000u;
    float f01 = u.f - 1.0f;
    const float minval = -0.99999994f;
    float uu = f01 * (1.0f - minval) + minval;
    uu = fmaxf(uu, minval);
    return 1.41421356f * erfinvf(uu);
}

// ---------------- merged prep: vnorm, qproj, W transpose, zeroing, key->bf16 ----------------
// blk 0: vnorm | 1..32: qproj | 33..544: Wt tiles | 545..607: zero e | 608..611: zero cv
// blk 612..8611: key -> relu -> bf16 (big path only)
__global__ __launch_bounds__(512) void prep_combined(
    const float* __restrict__ v_mono, const float* __restrict__ g_mono,
    const float* __restrict__ query, const float* __restrict__ wq_mono,
    const float* __restrict__ wq_chunk,
    const float* __restrict__ wk_mono, const float* __restrict__ wk_chunk,
    const float* __restrict__ key,
    float* __restrict__ vn, float* __restrict__ qp_mono, float* __restrict__ qp_chunk,
    u16* __restrict__ Wt, u16* __restrict__ kb,
    float* __restrict__ ezero, float* __restrict__ outcv)
{
    __shared__ float shf[512];
    __shared__ u16 tile[32][33];
    const int blk = blockIdx.x;
    const int tid = threadIdx.x;
    if (blk == 0){
        float v = v_mono[tid];
        shf[tid] = v * v;
        __syncthreads();
        for (int off = 256; off >= 1; off >>= 1){
            if (tid < off) shf[tid] += shf[tid + off];
            __syncthreads();
        }
        float g = g_mono[0];
        vn[tid] = g * v / sqrtf(shf[0]);
    } else if (blk <= 32){
        int b = (blk - 1) >> 1;
        int which = (blk - 1) & 1;
        const float* W = which ? wq_chunk : wq_mono;
        float* out = which ? qp_chunk : qp_mono;
        shf[tid] = query[b * 512 + tid];
        __syncthreads();
        float acc = 0.f;
        for (int k = 0; k < 512; k++) acc += shf[k] * W[k * 512 + tid];
        out[b * 512 + tid] = acc;
    } else if (blk <= 544){
        int idx = blk - 33;                     // 0..511
        int kt = (idx & 15) * 32, nt = (idx >> 4) * 32;
        int c = tid & 31, r = tid >> 5;         // 32 cols x 16 rows
        const float* src = (nt < 512) ? wk_mono : wk_chunk;
        int nbase = (nt < 512) ? nt : nt - 512;
#pragma unroll
        for (int i = 0; i < 2; i++){
            int kk = r + i * 16;
            tile[kk][c] = f2bf(src[(size_t)(kt + kk) * 512 + nbase + c]);
        }
        __syncthreads();
#pragma unroll
        for (int i = 0; i < 2; i++){
            int nn = r + i * 16;
            Wt[(size_t)(nt + nn) * 512 + kt + c] = tile[c][nn];
        }
    } else if (blk < 608){
        int i = ((blk - 545) * 512 + tid) * 4;   // zero e_mono|e_chunk (128000 floats)
        if (i < 128000){
            float4 z = {0.f, 0.f, 0.f, 0.f};
            *reinterpret_cast<float4*>(ezero + i) = z;
        }
    } else if (blk < 612){
        int i = ((blk - 608) * 512 + tid) * 4;   // zero cv accum target (8192 floats)
        float4 z = {0.f, 0.f, 0.f, 0.f};
        *reinterpret_cast<float4*>(outcv + i) = z;
    } else {
        size_t i = ((size_t)(blk - 612) * 512 + tid) * 8;
        float4 a = *reinterpret_cast<const float4*>(key + i);
        float4 b = *reinterpret_cast<const float4*>(key + i + 4);
        uint4 pk;
        pk.x = (u32)f2bf(fmaxf(a.x, 0.f)) | ((u32)f2bf(fmaxf(a.y, 0.f)) << 16);
        pk.y = (u32)f2bf(fmaxf(a.z, 0.f)) | ((u32)f2bf(fmaxf(a.w, 0.f)) << 16);
        pk.z = (u32)f2bf(fmaxf(b.x, 0.f)) | ((u32)f2bf(fmaxf(b.y, 0.f)) << 16);
        pk.w = (u32)f2bf(fmaxf(b.z, 0.f)) | ((u32)f2bf(fmaxf(b.w, 0.f)) << 16);
        *reinterpret_cast<uint4*>(kb + i) = pk;
    }
}

// ---------------- main GEMM + energy epilogue (m97 structure) ----------------
// grid 4096 1-D; bid -> (x, nT) such that the 8 nT sharing an A-tile are
// temporally adjacent AND congruent mod 8 (same-XCD heuristic -> L2 A-reuse).
// Staging via global_load_lds width=16 into LINEAR stride-32 LDS.
__global__ __launch_bounds__(256) void gemm_energy_pre(
    const u16* __restrict__ kb, const u16* __restrict__ Wt,
    const float* __restrict__ b_mono, const float* __restrict__ b_chunk,
    const float* __restrict__ vnorm, const float* __restrict__ v_chunk,
    const float* __restrict__ qp_mono, const float* __restrict__ qp_chunk,
    float* __restrict__ e_mono, float* __restrict__ e_chunk)
{
    __shared__ __align__(16) u16 As[128 * 32];
    __shared__ __align__(16) u16 Bs[128 * 32];
    const int bid = blockIdx.x;
    const int x = ((bid >> 6) << 3) + (bid & 7);
    if (x >= 500) return;
    const int nT = (bid >> 3) & 7;
    const int g0 = x * 128;
    const bool mono = (nT < 4);
    const int n0 = nT * 128;
    const int tid = threadIdx.x;
    const int lane = tid & 63;
    const int wave = tid >> 6;
    const int wm = wave >> 1, wn = wave & 1;
    const int l15 = lane & 15, quad = lane >> 4;

    f32x4 acc[4][4];
#pragma unroll
    for (int i = 0; i < 4; i++)
#pragma unroll
        for (int j = 0; j < 4; j++)
#pragma unroll
            for (int c = 0; c < 4; c++) acc[i][j][c] = 0.f;

    const u16* aG = kb + (size_t)g0 * 512;
    const u16* bG = Wt + (size_t)n0 * 512;

    for (int k0 = 0; k0 < 512; k0 += 32){
        // stage: 128 rows x 32 bf16 each = 512 x 16B slots; 2 slots/thread/matrix.
        // LDS dest byte offset = vid*16 == row*64 + part*16 (linear, lane-ordered).
#pragma unroll
        for (int it = 0; it < 2; it++){
            int vid = tid + it * 256;
            int row = vid >> 2;
            int part = vid & 3;
            gll16(aG + (size_t)row * 512 + k0 + part * 8, As + vid * 8);
            gll16(bG + (size_t)row * 512 + k0 + part * 8, Bs + vid * 8);
        }
        __syncthreads();   // drains vmcnt(0): LDS tiles complete for all waves
        bf16x8 af[4], bfr[4];
#pragma unroll
        for (int i = 0; i < 4; i++){
            af[i]  = *reinterpret_cast<const bf16x8*>(&As[(wm * 64 + i * 16 + l15) * 32 + quad * 8]);
            bfr[i] = *reinterpret_cast<const bf16x8*>(&Bs[(wn * 64 + i * 16 + l15) * 32 + quad * 8]);
        }
#pragma unroll
        for (int i = 0; i < 4; i++)
#pragma unroll
            for (int j = 0; j < 4; j++)
                acc[i][j] = __builtin_amdgcn_mfma_f32_16x16x32_bf16(af[i], bfr[j], acc[i][j], 0, 0, 0);
        __syncthreads();   // protect LDS before next-iter overwrite
    }

    // epilogue: e[row] += sum_cols v[col] * tanh(C + bias[col] + qproj[b][col])
    const float* qp = mono ? qp_mono : qp_chunk;
    float* edst = mono ? e_mono : e_chunk;
    float vv[4], bb[4]; int nc[4];
#pragma unroll
    for (int j = 0; j < 4; j++){
        int ncol = (n0 - (mono ? 0 : 512)) + wn * 64 + j * 16 + l15;
        nc[j] = ncol;
        vv[j] = mono ? vnorm[ncol] : v_chunk[ncol];
        bb[j] = mono ? b_mono[ncol] : b_chunk[ncol];
    }
#pragma unroll
    for (int i = 0; i < 4; i++){
#pragma unroll
        for (int r = 0; r < 4; r++){
            int g = g0 + wm * 64 + i * 16 + quad * 4 + r;
            int bidx = (u32)g / 4000u;
            float s = 0.f;
#pragma unroll
            for (int j = 0; j < 4; j++){
                float x2 = acc[i][j][r] + bb[j] + qp[bidx * 512 + nc[j]];
                s += vv[j] * tanh_fast(x2);
            }
            s += __shfl_xor(s, 1);
            s += __shfl_xor(s, 2);
            s += __shfl_xor(s, 4);
            s += __shfl_xor(s, 8);
            if (l15 == 0) atomicAdd(&edst[g], s);
        }
    }
}

// ---------------- fallback GEMM (small workspace): convert f32 key in-kernel ----------------
__global__ __launch_bounds__(256) void gemm_energy_f32(
    const float* __restrict__ key, const u16* __restrict__ Wt,
    const float* __restrict__ b_mono, const float* __restrict__ b_chunk,
    const float* __restrict__ vnorm, const float* __restrict__ v_chunk,
    const float* __restrict__ qp_mono, const float* __restrict__ qp_chunk,
    float* __restrict__ e_mono, float* __restrict__ e_chunk)
{
    __shared__ __align__(16) u16 As[128 * 40];
    __shared__ __align__(16) u16 Bs[128 * 40];
    const int tid = threadIdx.x;
    const int g0 = blockIdx.x * 128;
    const int nT = blockIdx.y;
    const bool mono = (nT < 4);
    const int n0 = nT * 128;
    const int lane = tid & 63;
    const int wave = tid >> 6;
    const int wm = wave >> 1, wn = wave & 1;
    const int l15 = lane & 15, quad = lane >> 4;

    f32x4 acc[4][4];
#pragma unroll
    for (int i = 0; i < 4; i++)
#pragma unroll
        for (int j = 0; j < 4; j++)
#pragma unroll
            for (int c = 0; c < 4; c++) acc[i][j][c] = 0.f;

    for (int k0 = 0; k0 < 512; k0 += 32){
        __syncthreads();
#pragma unroll
        for (int it = 0; it < 4; it++){
            int vid = tid + it * 256;
            int row = vid >> 3;
            int c4  = (vid & 7) << 2;
            float4 a = *reinterpret_cast<const float4*>(key + (size_t)(g0 + row) * 512 + k0 + c4);
            u32 p0 = (u32)f2bf(fmaxf(a.x, 0.f)) | ((u32)f2bf(fmaxf(a.y, 0.f)) << 16);
            u32 p1 = (u32)f2bf(fmaxf(a.z, 0.f)) | ((u32)f2bf(fmaxf(a.w, 0.f)) << 16);
            uint2 pk; pk.x = p0; pk.y = p1;
            *reinterpret_cast<uint2*>(&As[row * 40 + c4]) = pk;
        }
#pragma unroll
        for (int it = 0; it < 2; it++){
            int vid = tid + it * 256;
            int row = vid >> 2;
            int cb  = (vid & 3) << 3;
            uint4 b = *reinterpret_cast<const uint4*>(Wt + (size_t)(n0 + row) * 512 + k0 + cb);
            *reinterpret_cast<uint4*>(&Bs[row * 40 + cb]) = b;
        }
        __syncthreads();
        bf16x8 af[4], bfr[4];
#pragma unroll
        for (int i = 0; i < 4; i++){
            af[i]  = *reinterpret_cast<const bf16x8*>(&As[(wm * 64 + i * 16 + l15) * 40 + quad * 8]);
            bfr[i] = *reinterpret_cast<const bf16x8*>(&Bs[(wn * 64 + i * 16 + l15) * 40 + quad * 8]);
        }
#pragma unroll
        for (int i = 0; i < 4; i++)
#pragma unroll
            for (int j = 0; j < 4; j++)
                acc[i][j] = __builtin_amdgcn_mfma_f32_16x16x32_bf16(af[i], bfr[j], acc[i][j], 0, 0, 0);
    }

    const float* qp = mono ? qp_mono : qp_chunk;
    float* edst = mono ? e_mono : e_chunk;
    float vv[4], bb[4]; int nc[4];
#pragma unroll
    for (int j = 0; j < 4; j++){
        int ncol = (n0 - (mono ? 0 : 512)) + wn * 64 + j * 16 + l15;
        nc[j] = ncol;
        vv[j] = mono ? vnorm[ncol] : v_chunk[ncol];
        bb[j] = mono ? b_mono[ncol] : b_chunk[ncol];
    }
#pragma unroll
    for (int i = 0; i < 4; i++){
#pragma unroll
        for (int r = 0; r < 4; r++){
            int g = g0 + wm * 64 + i * 16 + quad * 4 + r;
            int bidx = (u32)g / 4000u;
            float s = 0.f;
#pragma unroll
            for (int j = 0; j < 4; j++){
                float x = acc[i][j][r] + bb[j] + qp[bidx * 512 + nc[j]];
                s += vv[j] * tanh_fast(x);
            }
            s += __shfl_xor(s, 1);
            s += __shfl_xor(s, 2);
            s += __shfl_xor(s, 4);
            s += __shfl_xor(s, 8);
            if (l15 == 0) atomicAdd(&edst[g], s);
        }
    }
}

// ---------------- per-batch scan: noise, p, alpha, chunk softmax, beta ----------------
// LDS stored at IDX(t)=t+(t>>4): lane stride becomes 17 words (bijective mod 32)
// -> moving-sum reads go from 32-way bank conflict to conflict-free.
#define IDX(t) ((t) + ((t) >> 4))

__global__ __launch_bounds__(256) void scan_energy(
    const float* __restrict__ e_mono, const float* __restrict__ e_chunk,
    const int* __restrict__ mask, const float* __restrict__ r_mono,
    float* __restrict__ out_alpha, float* __restrict__ beta)
{
    __shared__ float P[4256];     // p_choose, later reused as q = alpha/denom
    __shared__ float AL[4256];    // alpha
    __shared__ float SE[4256];    // softmax_exp
    __shared__ float red[256];
    const int b = blockIdx.x;
    const int tid = threadIdx.x;
    const float r = r_mono[0];
    const int t0 = tid * 16;

    float l[16];
    float lsum = 0.f;
#pragma unroll
    for (int i = 0; i < 16; i++){
        int t = t0 + i;
        if (t < T_LEN){
            int fl = b * T_LEN + t;
            float e = e_mono[fl] + r;
            if (mask[fl] == 0) e = NEG_INF;
            float x = e + jax_noise((u32)fl);
            float p = 1.0f / (1.0f + expf(-x));
            P[IDX(t)] = p;
            float om = 1.0f - p;
            om = fminf(fmaxf(om, 1e-6f), 1.0f);
            l[i] = logf(om);
            lsum += l[i];
        } else l[i] = 0.f;
    }
    red[tid] = lsum;
    __syncthreads();
#pragma unroll
    for (int off = 1; off < 256; off <<= 1){
        float v = (tid >= off) ? red[tid - off] : 0.f;
        __syncthreads();
        red[tid] += v;
        __syncthreads();
    }
    float run = red[tid] - lsum;
#pragma unroll
    for (int i = 0; i < 16; i++){
        int t = t0 + i;
        if (t < T_LEN){
            float alpha = P[IDX(t)] * expf(run);
            run += l[i];
            AL[IDX(t)] = alpha;
            out_alpha[b * T_LEN + t] = alpha;
        }
    }

    float ec[16]; float lmax = NEG_INF;
#pragma unroll
    for (int i = 0; i < 16; i++){
        int t = t0 + i;
        if (t < T_LEN){
            int fl = b * T_LEN + t;
            float e = e_chunk[fl];
            if (mask[fl] == 0) e = NEG_INF;
            ec[i] = e;
            lmax = fmaxf(lmax, e);
        } else ec[i] = NEG_INF;
    }
    __syncthreads();
    red[tid] = lmax;
    __syncthreads();
    for (int off = 128; off >= 1; off >>= 1){
        if (tid < off) red[tid] = fmaxf(red[tid], red[tid + off]);
        __syncthreads();
    }
    float m = red[0];
#pragma unroll
    for (int i = 0; i < 16; i++){
        int t = t0 + i;
        if (t < T_LEN) SE[IDX(t)] = fmaxf(expf(ec[i] - m), 1e-5f);
    }
    __syncthreads();
#pragma unroll
    for (int i = 0; i < 16; i++){
        int t = t0 + i;
        if (t < T_LEN){
            float d = 0.f;
            int lo = t - 7; if (lo < 0) lo = 0;
            for (int s = lo; s <= t; s++) d += SE[IDX(s)];   // moving_sum back=7
            P[IDX(t)] = AL[IDX(t)] / d;                      // q (TEMP=1)
        }
    }
    __syncthreads();
#pragma unroll
    for (int i = 0; i < 16; i++){
        int t = t0 + i;
        if (t < T_LEN){
            float s2 = 0.f;
            int hi = t + 7; if (hi > T_LEN - 1) hi = T_LEN - 1;
            for (int s = t; s <= hi; s++) s2 += P[IDX(s)];   // moving_sum fwd=7
            beta[b * T_LEN + t] = SE[IDX(t)] * s2;
        }
    }
}

// ---------------- cv = sum_t beta[t] * value[t,:] (into d_out directly) ----------------
__global__ __launch_bounds__(256) void cv_accum(const float* __restrict__ value,
                                                const float* __restrict__ beta,
                                                float* __restrict__ outcv){
    const int b = blockIdx.x >> 4;
    const int c = blockIdx.x & 15;
    const int tid = threadIdx.x;
    __shared__ float bsh[250];
    int tstart = c * 250;
    if (tid < 250) bsh[tid] = beta[b * T_LEN + tstart + tid];
    __syncthreads();
    int dl = (tid & 127) * 4;
    int trow = tid >> 7;
    float4 a = {0.f, 0.f, 0.f, 0.f};
    for (int t = trow; t < 250; t += 2){
        float bt = bsh[t];
        float4 v = *reinterpret_cast<const float4*>(
            value + (size_t)(b * T_LEN + tstart + t) * 512 + dl);
        a.x += bt * v.x; a.y += bt * v.y; a.z += bt * v.z; a.w += bt * v.w;
    }
    atomicAdd(&outcv[b * 512 + dl + 0], a.x);
    atomicAdd(&outcv[b * 512 + dl + 1], a.y);
    atomicAdd(&outcv[b * 512 + dl + 2], a.z);
    atomicAdd(&outcv[b * 512 + dl + 3], a.w);
}

// ---------------- launch ----------------
extern "C" void kernel_launch(void* const* d_in, const int* in_sizes, int n_in,
                              void* d_out, int out_size, void* d_ws, size_t ws_size,
                              hipStream_t stream)
{
    const float* key      = (const float*)d_in[0];
    const float* value    = (const float*)d_in[1];
    const float* query    = (const float*)d_in[2];
    const int*   mask     = (const int*)d_in[3];
    const float* wk_mono  = (const float*)d_in[4];
    const float* bk_mono  = (const float*)d_in[5];
    const float* wq_mono  = (const float*)d_in[6];
    const float* v_mono   = (const float*)d_in[7];
    const float* g_mono   = (const float*)d_in[8];
    const float* r_mono   = (const float*)d_in[9];
    const float* wk_chunk = (const float*)d_in[10];
    const float* bk_chunk = (const float*)d_in[11];
    const float* wq_chunk = (const float*)d_in[12];
    const float* v_chunk  = (const float*)d_in[13];

    float* ws      = (float*)d_ws;
    float* e_mono  = ws;                 // 64000
    float* e_chunk = ws + 64000;         // 64000
    float* beta    = ws + 136192;        // 64000
    float* qp_mono = ws + 200192;        // 8192
    float* qp_chunk= ws + 208384;        // 8192
    float* vnorm   = ws + 216576;        // 512
    u16*   Wt      = (u16*)(ws + 217088);// 1024x512 bf16 (1 MB)
    u16*   kb      = (u16*)(ws + 479232);// 64000x512 bf16 (65.5 MB) if it fits

    const size_t NEED = 479232u * 4u + (size_t)64000 * 512 * 2;
    const bool big = ws_size >= NEED;

    // no hipMemsetAsync: e/cv zeroing folded into prep_combined blocks 545..611
    prep_combined<<<big ? 8612 : 612, 512, 0, stream>>>(
        v_mono, g_mono, query, wq_mono, wq_chunk, wk_mono, wk_chunk, key,
        vnorm, qp_mono, qp_chunk, Wt, kb, e_mono, (float*)d_out);

    if (big){
        gemm_energy_pre<<<4096, 256, 0, stream>>>(kb, Wt, bk_mono, bk_chunk,
                                                  vnorm, v_chunk, qp_mono, qp_chunk,
                                                  e_mono, e_chunk);
    } else {
        gemm_energy_f32<<<dim3(500, 8), 256, 0, stream>>>(key, Wt, bk_mono, bk_chunk,
                                                          vnorm, v_chunk, qp_mono, qp_chunk,
                                                          e_mono, e_chunk);
    }
    scan_energy<<<16, 256, 0, stream>>>(e_mono, e_chunk, mask, r_mono,
                                        (float*)d_out + 8192, beta);
    cv_accum<<<256, 256, 0, stream>>>(value, beta, (float*)d_out);
}